// Round 12
// baseline (585.173 us; speedup 1.0000x reference)
//
#include <hip/hip_runtime.h>

#define NEGV (-10000.0f)

constexpr int B_ = 512;
constexpr int S_ = 1024;
constexpr int NL_ = 49;
constexpr int L_ = 51;   // NL + 2; start = 49, end = 50

__device__ __forceinline__ float readlane_f(float v, int l) {
    return __int_as_float(__builtin_amdgcn_readlane(__float_as_int(v), l));
}

template <int CTRL>
__device__ __forceinline__ float dpp_max_step(float v) {
    int sh = __builtin_amdgcn_update_dpp(__float_as_int(v), __float_as_int(v),
                                         CTRL, 0xf, 0xf, false);
    return fmaxf(v, __int_as_float(sh));
}

// Full 64-lane max -> wave-uniform scalar (SGPR). Pure VALU (DPP), no LDS pipe.
__device__ __forceinline__ float wave_max_sgpr(float v) {
    v = dpp_max_step<0x111>(v);  // row_shr:1
    v = dpp_max_step<0x112>(v);  // row_shr:2
    v = dpp_max_step<0x114>(v);  // row_shr:4
    v = dpp_max_step<0x118>(v);  // row_shr:8
    v = dpp_max_step<0x142>(v);  // row_bcast:15
    v = dpp_max_step<0x143>(v);  // row_bcast:31
    return readlane_f(v, 63);
}

// Wave rotate-right by 1 (DPP wf_rr1 = 0x13C): lane n receives lane (n-1)&63.
// Same direction family as row_shr (lane n <- lane n-1), which wave_max_sgpr
// depends on and which validated bit-exact in R2-R9.
__device__ __forceinline__ float dpp_ror1(float v) {
    int iv = __float_as_int(v);
    return __int_as_float(
        __builtin_amdgcn_update_dpp(iv, iv, 0x13C, 0xf, 0xf, false));
}

__global__ __launch_bounds__(64, 1) void crf_fwd(
    const float* __restrict__ logits,      // (B, S, NL)
    const float* __restrict__ transition,  // (L, L)
    const int*   __restrict__ labels,      // (B, S)
    const int*   __restrict__ lens,        // (B,)
    float*       __restrict__ out)         // (B,)
{
    const int b    = blockIdx.x;
    const int lane = threadIdx.x;
    const int len  = __builtin_amdgcn_readfirstlane(lens[b]);  // wave-uniform, >= 1

    const float* __restrict__ lg  = logits + (size_t)b * (S_ * NL_);
    const int*   __restrict__ lab = labels + (size_t)b * S_;

    // ---- permuted transition row for the systolic rotation ----
    // After s ror1 steps, lane i holds P_{(i-s)&63}. So to accumulate
    // y_i = sum_j E[i][j] * P_j we need Eperm[s] = exp(T[lane][(lane-s)&63]),
    // zeroed when row or source-col >= NL_.
    const float* trow = transition + ((lane < NL_) ? lane : 0) * L_;
    float Eperm[64];
    #pragma unroll
    for (int s = 0; s < 64; ++s) {
        int j = (lane - s) & 63;                     // source state after s rots
        float tv = trow[(j < NL_) ? j : 0];          // in-bounds always
        Eperm[s] = (lane < NL_ && j < NL_) ? __expf(tv) : 0.0f;
    }
    float estart = __expf(trow[NL_]);                // exp(T[lane][start])
    float Tend   = (lane < L_) ? transition[(L_ - 1) * L_ + lane] : NEGV;

    // ---- gold score: lane-parallel over time ----
    float g = 0.0f;
    for (int t = lane; t < S_; t += 64) {
        if (t < len) {
            int c = lab[t];
            int p = (t == 0) ? (L_ - 2) : lab[t - 1];
            g += lg[t * NL_ + c] + transition[c * L_ + p];
            if (t == len - 1) g += transition[(L_ - 1) * L_ + c];  // end transition
        }
    }
    #pragma unroll
    for (int o = 32; o >= 1; o >>= 1) g += __shfl_xor(g, o, 64);

    // ---- forward scan, exp-space linear recurrence, systolic rotation ----
    // Lane i holds P_i. P_t = 2^{-k_t} * D_t * E * P_{t-1}.
    // Scale is an exact power of 2 from the FRESH max of the state being
    // consumed: m_t stays bounded -> no denormal drift, no overflow.
    float P = 0.0f;
    if (lane < NL_) P = __expf(lg[lane]) * estart;   // t = 0

    int   S = 0;          // total base-2 shifts (wave-uniform)
    int   kc;             // shift applied at the upcoming step
    float scale_f;        // 2^{-kc}, exact
    auto mk_scale = [&](float Mx) {
        int e = (__float_as_int(Mx) >> 23) & 255;
        if (e < 1) e = 1;                            // zero/denormal guard
        kc      = e - 127;
        scale_f = __int_as_float((254 - e) << 23);   // exact 2^{-kc}
    };
    mk_scale(wave_max_sgpr(P));

    auto loadlg = [&](int t) -> float {
        float v = NEGV;
        if (lane < NL_) v = lg[t * NL_ + lane];
        return v;
    };

    float b0 = loadlg(1), b1 = loadlg(2), b2 = loadlg(3), b3 = loadlg(4);
    float b4 = loadlg(5), b5 = loadlg(6), b6 = loadlg(7), b7 = loadlg(8);

    auto substep = [&](float cur, int t) {
        float rB = __shfl_xor(P, 32, 64);    // P_{(i-32)&63}: seeds chain B (s=32)
        float d  = __expf(cur) * scale_f;    // off the rotation chain
        float rA = P;                        // P_{(i-0)&63}: seeds chain A (s=0)
        float yA0 = 0.f, yA1 = 0.f, yB0 = 0.f, yB1 = 0.f;
        #pragma unroll
        for (int s = 0; s < 32; s += 2) {
            yA0 = fmaf(Eperm[s],      rA, yA0);  rA = dpp_ror1(rA);
            yA1 = fmaf(Eperm[s + 1],  rA, yA1);  rA = dpp_ror1(rA);
            yB0 = fmaf(Eperm[s + 32], rB, yB0);  rB = dpp_ror1(rB);
            yB1 = fmaf(Eperm[s + 33], rB, yB1);  rB = dpp_ror1(rB);
        }
        float y  = (yA0 + yA1) + (yB0 + yB1);
        float Pn = d * y;                    // lanes >= NL_: Eperm==0 -> y==0 -> 0
        const bool live = (t < len);         // wave-uniform
        if (live) { P = Pn; S += kc; }
        mk_scale(wave_max_sgpr(Pn));         // FRESH max -> stable normalization
    };

    const int tEnd = 1 + (((len - 1) + 7) & ~7);   // steps t = 1 .. len-1, padded to 8
    for (int t = 1; t < tEnd; t += 8) {
        int t8  = t + 8;  t8  = (t8  < S_) ? t8  : (S_ - 1);
        int t9  = t + 9;  t9  = (t9  < S_) ? t9  : (S_ - 1);
        int t10 = t + 10; t10 = (t10 < S_) ? t10 : (S_ - 1);
        int t11 = t + 11; t11 = (t11 < S_) ? t11 : (S_ - 1);
        int t12 = t + 12; t12 = (t12 < S_) ? t12 : (S_ - 1);
        int t13 = t + 13; t13 = (t13 < S_) ? t13 : (S_ - 1);
        int t14 = t + 14; t14 = (t14 < S_) ? t14 : (S_ - 1);
        int t15 = t + 15; t15 = (t15 < S_) ? t15 : (S_ - 1);
        substep(b0, t + 0); b0 = loadlg(t8);
        substep(b1, t + 1); b1 = loadlg(t9);
        substep(b2, t + 2); b2 = loadlg(t10);
        substep(b3, t + 3); b3 = loadlg(t11);
        substep(b4, t + 4); b4 = loadlg(t12);
        substep(b5, t + 5); b5 = loadlg(t13);
        substep(b6, t + 6); b6 = loadlg(t14);
        substep(b7, t + 7); b7 = loadlg(t15);
    }

    // ---- back to log-space ONCE: alpha_i = log(P_i) + S*ln2 ----
    float alpha = logf(P) + (float)S * 0.69314718056f;   // P==0 -> -inf (ok in LSE)

    // ---- norm = LSE_i(alpha_i + T[end, i]) ----
    float x = (lane < L_) ? (alpha + Tend) : NEGV;
    float mx = x;
    #pragma unroll
    for (int o = 32; o >= 1; o >>= 1) mx = fmaxf(mx, __shfl_xor(mx, o, 64));
    float e = __expf(x - mx);
    #pragma unroll
    for (int o = 32; o >= 1; o >>= 1) e += __shfl_xor(e, o, 64);
    float norm = mx + __logf(e);

    if (lane == 0) out[b] = g - norm;
}

extern "C" void kernel_launch(void* const* d_in, const int* in_sizes, int n_in,
                              void* d_out, int out_size, void* d_ws, size_t ws_size,
                              hipStream_t stream) {
    const float* logits     = (const float*)d_in[0];
    const float* transition = (const float*)d_in[1];
    const int*   labels     = (const int*)d_in[2];
    const int*   lens       = (const int*)d_in[3];
    float*       out        = (float*)d_out;
    crf_fwd<<<dim3(B_), dim3(64), 0, stream>>>(logits, transition, labels, lens, out);
}